// Round 1
// baseline (539.782 us; speedup 1.0000x reference)
//
#include <hip/hip_runtime.h>
#include <hip/hip_bf16.h>

// Problem constants
// B=2048, NF=64, FD=32, S=32, D=32, OD=32
#define BT        16     // b-tile per block
#define NTHREADS  256

__global__ __launch_bounds__(NTHREADS, 2) void tn_fused_kernel(
    const float* __restrict__ x, const float* __restrict__ L,
    const float* __restrict__ R, const float* __restrict__ O,
    const float* __restrict__ bias, float* __restrict__ out)
{
    const int s  = blockIdx.y;          // 0..31
    const int b0 = blockIdx.x * BT;     // b-tile base
    const int t  = threadIdx.x;

    __shared__ float xl[BT][32];
    __shared__ float xr[BT][32];
    __shared__ __hip_bfloat16 Abuf[BT * 1024];  // A, later overwritten by M
    __shared__ __hip_bfloat16 Bbuf[BT * 1024];  // B, later O staging (16384 = 512x32 chunk)

    // ---- load x tiles ----
    for (int i = t; i < BT * 32; i += NTHREADS) {
        int b = i >> 5, f = i & 31;
        xl[b][f] = x[((size_t)(b0 + b) * 64 + 2 * s) * 32 + f];
        xr[b][f] = x[((size_t)(b0 + b) * 64 + 2 * s + 1) * 32 + f];
    }
    __syncthreads();

    const float* Ls = L + (size_t)s * 32768;
    const float* Rs = R + (size_t)s * 32768;
    const float* Os = O + (size_t)s * 32768;

    // ---- phase 2: A[b][am] = sum_f xl[b][f] * L[s][f][am], am = t + 256*i ----
    {
        float acc[BT][4];
        #pragma unroll
        for (int b = 0; b < BT; ++b)
            #pragma unroll
            for (int i = 0; i < 4; ++i) acc[b][i] = 0.f;

        for (int f = 0; f < 32; ++f) {
            float lv[4];
            #pragma unroll
            for (int i = 0; i < 4; ++i) lv[i] = Ls[f * 1024 + t + NTHREADS * i];
            #pragma unroll
            for (int b = 0; b < BT; ++b) {
                float xv = xl[b][f];
                #pragma unroll
                for (int i = 0; i < 4; ++i) acc[b][i] += xv * lv[i];
            }
        }
        #pragma unroll
        for (int b = 0; b < BT; ++b)
            #pragma unroll
            for (int i = 0; i < 4; ++i)
                Abuf[b * 1024 + t + NTHREADS * i] = __float2bfloat16(acc[b][i]);

        // B[b][an] = sum_f xr[b][f] * R[s][f][an]
        #pragma unroll
        for (int b = 0; b < BT; ++b)
            #pragma unroll
            for (int i = 0; i < 4; ++i) acc[b][i] = 0.f;

        for (int f = 0; f < 32; ++f) {
            float rv[4];
            #pragma unroll
            for (int i = 0; i < 4; ++i) rv[i] = Rs[f * 1024 + t + NTHREADS * i];
            #pragma unroll
            for (int b = 0; b < BT; ++b) {
                float xv = xr[b][f];
                #pragma unroll
                for (int i = 0; i < 4; ++i) acc[b][i] += xv * rv[i];
            }
        }
        #pragma unroll
        for (int b = 0; b < BT; ++b)
            #pragma unroll
            for (int i = 0; i < 4; ++i)
                Bbuf[b * 1024 + t + NTHREADS * i] = __float2bfloat16(acc[b][i]);
    }
    __syncthreads();

    // ---- phase 3: M[b][m*32+n] = sum_a A[b][a*32+m] * B[b][a*32+n]
    //      each thread owns mn = 4t..4t+3 (same m); M overwrites Abuf[b] ----
    {
        const int mn0 = 4 * t;
        const int m   = mn0 >> 5;
        const int n0  = mn0 & 31;
        for (int b = 0; b < BT; ++b) {
            float macc[4] = {0.f, 0.f, 0.f, 0.f};
            #pragma unroll
            for (int a = 0; a < 32; ++a) {
                float av = __bfloat162float(Abuf[b * 1024 + a * 32 + m]);
                #pragma unroll
                for (int i = 0; i < 4; ++i)
                    macc[i] += av * __bfloat162float(Bbuf[b * 1024 + a * 32 + n0 + i]);
            }
            __syncthreads();   // all reads of Abuf[b] complete before overwrite
            #pragma unroll
            for (int i = 0; i < 4; ++i)
                Abuf[b * 1024 + mn0 + i] = __float2bfloat16(macc[i]);
        }
    }
    __syncthreads();

    // ---- phase 4: out[b][o] = sum_mn M[b][mn] * O[s][mn][o] + bias[s][o]
    //      O staged into Bbuf in two 512-row (mn) chunks of 32 KB ----
    {
        const int o  = t & 31;
        const int bq = t >> 5;      // 0..7
        float acc[2] = {0.f, 0.f};  // b = bq, bq+8

        for (int c = 0; c < 2; ++c) {
            for (int i = t; i < 512 * 32; i += NTHREADS)
                Bbuf[i] = __float2bfloat16(Os[c * 16384 + i]);
            __syncthreads();
            #pragma unroll
            for (int p = 0; p < 2; ++p) {
                const int b = bq + 8 * p;
                float a2 = 0.f;
                for (int mn = 0; mn < 512; ++mn)
                    a2 += __bfloat162float(Abuf[b * 1024 + c * 512 + mn]) *
                          __bfloat162float(Bbuf[mn * 32 + o]);
                acc[p] += a2;
            }
            __syncthreads();
        }

        const float bv = bias[s * 32 + o];
        #pragma unroll
        for (int p = 0; p < 2; ++p)
            out[(size_t)(b0 + bq + 8 * p) * 1024 + s * 32 + o] = acc[p] + bv;
    }
}

extern "C" void kernel_launch(void* const* d_in, const int* in_sizes, int n_in,
                              void* d_out, int out_size, void* d_ws, size_t ws_size,
                              hipStream_t stream) {
    const float* x    = (const float*)d_in[0];
    const float* L    = (const float*)d_in[1];
    const float* R    = (const float*)d_in[2];
    const float* O    = (const float*)d_in[3];
    const float* bias = (const float*)d_in[4];
    float* out = (float*)d_out;

    dim3 grid(2048 / BT, 32);   // (b-tiles, s)
    dim3 block(NTHREADS);
    tn_fused_kernel<<<grid, block, 0, stream>>>(x, L, R, O, bias, out);
}

// Round 2
// 88.033 us; speedup vs baseline: 6.1316x; 6.1316x over previous
//
#include <hip/hip_runtime.h>
#include <hip/hip_bf16.h>

// B=2048, NF=64, FD=32, S=32, D=32, OD=32
typedef __attribute__((ext_vector_type(8)))  short bf16x8;
typedef __attribute__((ext_vector_type(4)))  float f32x4;
typedef __attribute__((ext_vector_type(16))) float f32x16;

__device__ __forceinline__ short f2bf(float x) {
    __bf16 h = (__bf16)x;
    return __builtin_bit_cast(short, h);
}

// ---------------- weight pre-conversion / pre-transpose ----------------
// Lp[s][m*32+a][f] = L[s][f][a][m]   (bf16)
// Rp[s][n*32+a][g] = R[s][g][a][n]   (bf16)
// Op[s][o][m*32+n] = O[s][m][n][o]   (bf16)
__global__ __launch_bounds__(64) void conv_kernel(
    const float* __restrict__ Lg, const float* __restrict__ Rg,
    const float* __restrict__ Og,
    short* __restrict__ Lp, short* __restrict__ Rp, short* __restrict__ Op)
{
    __shared__ float tile[32][33];
    const int which = blockIdx.y;
    const int s = blockIdx.x >> 5, q = blockIdx.x & 31;  // q = a (L/R) or m (O)
    const int t = threadIdx.x, tl = t & 31, th = t >> 5;

    if (which < 2) {
        const float* src = (which == 0) ? Lg : Rg;
        short* dst = (which == 0) ? Lp : Rp;
        #pragma unroll
        for (int j = 0; j < 16; ++j) {
            int fr = 2*j + th;   // f index
            tile[tl][fr] = src[(((size_t)s*32 + fr)*32 + q)*32 + tl];  // tile[m][f]
        }
        __syncthreads();
        #pragma unroll
        for (int j = 0; j < 16; ++j) {
            int mr = 2*j + th;   // m index
            dst[((size_t)s*1024 + mr*32 + q)*32 + tl] = f2bf(tile[mr][tl]);
        }
    } else {
        #pragma unroll
        for (int j = 0; j < 16; ++j) {
            int nr = 2*j + th;   // n index
            tile[tl][nr] = Og[((size_t)s*1024 + q*32 + nr)*32 + tl];   // tile[o][n]
        }
        __syncthreads();
        #pragma unroll
        for (int j = 0; j < 16; ++j) {
            int orow = 2*j + th;
            Op[((size_t)s*32 + orow)*1024 + q*32 + tl] = f2bf(tile[orow][tl]);
        }
    }
}

// ---------------- fused MFMA main kernel ----------------
// grid: 2048 flat blocks; s = bid&31 (XCD = s%8 -> per-XCD L2 holds 4 s-slices)
// block: 512 threads = 8 waves, BT=32 b-rows per block
__global__ __launch_bounds__(512, 2) void tn_mfma_kernel(
    const float* __restrict__ x,
    const short* __restrict__ Lp, const short* __restrict__ Rp,
    const short* __restrict__ Op,
    const float* __restrict__ bias, float* __restrict__ out)
{
    __shared__ short xlr[2][32][32];   // 4 KB   [side][b][f] bf16
    __shared__ short AB[2][32*1040];   // 130 KB [side][b][1024+pad] bf16 (A/B, then M over A)
    __shared__ float red[1024];        // 4 KB   out-phase k-split partials

    const int bid = blockIdx.x;
    const int s  = bid & 31;
    const int b0 = (bid >> 5) << 5;
    const int t = threadIdx.x;
    const int l = t & 63, wid = t >> 6;
    const int lhi = l >> 4, llo = l & 15;

    // ---- stage x tile as bf16 (coalesced) ----
    #pragma unroll
    for (int i = 0; i < 4; ++i) {
        int idx = t + 512*i;
        int b = idx >> 6, ff = idx & 63;
        float v = x[(size_t)(b0 + b)*2048 + s*64 + ff];
        xlr[ff >> 5][b][ff & 31] = f2bf(v);
    }
    __syncthreads();

    // ---- phase A/B: A[b, am'] = xL[b,f] @ Lp[f, am']  (am' = m*32+a, m-major) ----
    // 16x16x32: wave -> mtile = wid&1, ntiles (wid>>1)*16 .. +15
    {
        const int mtile = wid & 1, ntb = (wid >> 1) * 16;
        #pragma unroll
        for (int p = 0; p < 2; ++p) {
            const short* W = (p ? Rp : Lp) + (size_t)s * 32768;
            bf16x8 af = *reinterpret_cast<const bf16x8*>(&xlr[p][16*mtile + llo][8*lhi]);
            #pragma unroll
            for (int j = 0; j < 16; ++j) {
                int col = (ntb + j)*16 + llo;                      // am' column
                bf16x8 bf = *reinterpret_cast<const bf16x8*>(W + col*32 + 8*lhi);
                f32x4 d = __builtin_amdgcn_mfma_f32_16x16x32_bf16(af, bf, (f32x4)(0.0f), 0, 0, 0);
                // store with XOR slot swizzle: row b, [m][a] layout, 16B slots
                int m = col >> 5, a = col & 31;
                int pos = (((m*4 + (a >> 3)) ^ (m & 7)) << 3) + (a & 7);
                #pragma unroll
                for (int r = 0; r < 4; ++r)
                    AB[p][(16*mtile + 4*lhi + r)*1040 + pos] = f2bf(d[r]);
            }
        }
    }
    __syncthreads();

    // ---- phase M: per b, M[m,n] = sum_a A[b,a,m] * B[b,a,n]  (32x32x16, 2 k-steps)
    {
        const int mrow = l & 31, half = l >> 5;
        #pragma unroll
        for (int bi = 0; bi < 4; ++bi) {
            int b = wid*4 + bi;
            f32x16 acc = (f32x16)(0.0f);
            #pragma unroll
            for (int kst = 0; kst < 2; ++kst) {
                int a0 = kst*16 + 8*half;
                int off = b*1040 + (((mrow*4 + (a0 >> 3)) ^ (mrow & 7)) << 3);
                bf16x8 aop = *reinterpret_cast<const bf16x8*>(&AB[0][off]);
                bf16x8 bop = *reinterpret_cast<const bf16x8*>(&AB[1][off]);
                acc = __builtin_amdgcn_mfma_f32_32x32x16_bf16(aop, bop, acc, 0, 0, 0);
            }
            // M[b][m*32+n] overwrites A region (wave-local b, dep-chain ordered)
            #pragma unroll
            for (int r = 0; r < 16; ++r) {
                int mr = (r & 3) + 8*(r >> 2) + 4*half;
                AB[0][b*1040 + mr*32 + mrow] = f2bf(acc[r]);
            }
        }
    }
    __syncthreads();

    // ---- out phase: out[b,o] = sum_mn M[b,mn] * Op[o,mn]  (16x16x32, K=1024 split 2) ----
    {
        const int mt = wid >> 2, nt = (wid >> 1) & 1, kh = wid & 1;
        const int brow = 16*mt + llo, orow = 16*nt + llo;
        const short* Ob = Op + ((size_t)s*32 + orow)*1024 + kh*512 + 8*lhi;
        const short* Mb = &AB[0][brow*1040 + kh*512 + 8*lhi];
        f32x4 acc = (f32x4)(0.0f);
        #pragma unroll
        for (int ks = 0; ks < 16; ++ks) {
            bf16x8 afrag = *reinterpret_cast<const bf16x8*>(Mb + ks*32);
            bf16x8 bfrag = *reinterpret_cast<const bf16x8*>(Ob + ks*32);
            acc = __builtin_amdgcn_mfma_f32_16x16x32_bf16(afrag, bfrag, acc, 0, 0, 0);
        }
        const int tile4 = mt*2 + nt;
        if (kh) *reinterpret_cast<f32x4*>(&red[tile4*256 + l*4]) = acc;
        __syncthreads();
        if (!kh) {
            f32x4 oth = *reinterpret_cast<const f32x4*>(&red[tile4*256 + l*4]);
            float bv = bias[s*32 + orow];
            #pragma unroll
            for (int r = 0; r < 4; ++r) {
                int b = 16*mt + 4*lhi + r;
                out[(size_t)(b0 + b)*1024 + s*32 + orow] = acc[r] + oth[r] + bv;
            }
        }
    }
}

extern "C" void kernel_launch(void* const* d_in, const int* in_sizes, int n_in,
                              void* d_out, int out_size, void* d_ws, size_t ws_size,
                              hipStream_t stream) {
    const float* x    = (const float*)d_in[0];
    const float* L    = (const float*)d_in[1];
    const float* R    = (const float*)d_in[2];
    const float* O    = (const float*)d_in[3];
    const float* bias = (const float*)d_in[4];
    float* out = (float*)d_out;

    short* Lp = (short*)d_ws;            // 32*1024*32 bf16 = 2 MB
    short* Rp = Lp + 32*1024*32;         // 2 MB
    short* Op = Rp + 32*1024*32;         // 2 MB

    conv_kernel<<<dim3(1024, 3), 64, 0, stream>>>(L, R, O, Lp, Rp, Op);
    tn_mfma_kernel<<<dim3(2048), 512, 0, stream>>>(x, Lp, Rp, Op, bias, out);
}

// Round 3
// 42.737 us; speedup vs baseline: 12.6304x; 2.0599x over previous
//
#include <hip/hip_runtime.h>
#include <hip/hip_bf16.h>

// B=2048, NF=64, FD=32, S=32, D=32, OD=32
typedef __attribute__((ext_vector_type(4)))  _Float16 h4;
typedef __attribute__((ext_vector_type(8)))  _Float16 h8;
typedef __attribute__((ext_vector_type(4)))  float f32x4;
typedef __attribute__((ext_vector_type(16))) float f32x16;

// ---------------- transpose/convert: Rb[s][g][n][a], Op[s][o][m*32+n] (f16) ----
__global__ __launch_bounds__(64) void conv_kernel(
    const float* __restrict__ Rg, const float* __restrict__ Og,
    _Float16* __restrict__ Rb, _Float16* __restrict__ Op)
{
    __shared__ float tile[32][33];
    const int which = blockIdx.y;
    const int s = blockIdx.x >> 5, q = blockIdx.x & 31;   // q = g (Rb) or m (Op)
    const int t = threadIdx.x, tl = t & 31, th = t >> 5;

    if (which == 0) {
        // Rb[s][g][n][a] = R[s][g][a][n]
        #pragma unroll
        for (int j = 0; j < 16; ++j) {
            int ar = 2*j + th;
            tile[tl][ar] = Rg[(((size_t)s*32 + q)*32 + ar)*32 + tl];   // tile[n][a]
        }
        __syncthreads();
        #pragma unroll
        for (int j = 0; j < 16; ++j) {
            int nr = 2*j + th;
            Rb[(((size_t)s*32 + q)*32 + nr)*32 + tl] = (_Float16)tile[nr][tl];
        }
    } else {
        // Op[s][o][m*32+n] = O[s][m][n][o]
        #pragma unroll
        for (int j = 0; j < 16; ++j) {
            int nr = 2*j + th;
            tile[tl][nr] = Og[(((size_t)s*32 + q)*32 + nr)*32 + tl];   // tile[o][n]
        }
        __syncthreads();
        #pragma unroll
        for (int j = 0; j < 16; ++j) {
            int orow = 2*j + th;
            Op[((size_t)s*32 + orow)*1024 + q*32 + tl] = (_Float16)tile[orow][tl];
        }
    }
}

// ---------------- T[s][o][f*32+g] = sum_{a,m,n} L[s,f,a,m] R[s,g,a,n] O[s,m,n,o] ----
// grid: 1024 blocks (s = bid&31, f = bid>>5), 256 threads = 4 waves
__global__ __launch_bounds__(256) void tmake_kernel(
    const float* __restrict__ Lg, const _Float16* __restrict__ Rb,
    const _Float16* __restrict__ Op, _Float16* __restrict__ To)
{
    __shared__ __align__(16) char Wl[65536];   // W[g][m*32+n] f16, XOR-swizzled
    __shared__ float Ltile[32][33];            // L[s,f][a][m]

    const int bid = blockIdx.x;
    const int s = bid & 31, f = bid >> 5;
    const int t = threadIdx.x, wid = t >> 6, l = t & 63;
    const int llo = l & 15, lhi = l >> 4;

    #pragma unroll
    for (int i = 0; i < 4; ++i) {
        int idx = i*256 + t, a = idx >> 5, m = idx & 31;
        Ltile[a][m] = Lg[(((size_t)s*32 + f)*32 + a)*32 + m];
    }
    __syncthreads();

    // A-frags for GEMM1: row m = mt*16+llo, k = a = 8*lhi+j
    h8 afrag[2];
    #pragma unroll
    for (int mt = 0; mt < 2; ++mt)
        #pragma unroll
        for (int j = 0; j < 8; ++j)
            afrag[mt][j] = (_Float16)Ltile[8*lhi + j][mt*16 + llo];

    const _Float16* Rbs = Rb + (size_t)s*32768;
    const _Float16* Ops = Op + (size_t)s*32768;

    // GEMM1: W[m, gn] = sum_a Ltile[m,a] * Rb[gn,a]  (M=32, N=1024, K=32)
    #pragma unroll 4
    for (int nt = 0; nt < 16; ++nt) {
        int col = (wid*16 + nt)*16 + llo;                 // gn
        h8 bfrag = *(const h8*)(Rbs + col*32 + 8*lhi);
        int g = col >> 5, n = col & 31;
        #pragma unroll
        for (int mt = 0; mt < 2; ++mt) {
            f32x4 c = __builtin_amdgcn_mfma_f32_16x16x32_f16(afrag[mt], bfrag, (f32x4)(0.0f), 0, 0, 0);
            #pragma unroll
            for (int r = 0; r < 4; ++r) {
                int m = mt*16 + 4*lhi + r;
                int byte = (g*2048 + (m*32 + n)*2) ^ ((g & 7) << 4);
                *(_Float16*)(Wl + byte) = (_Float16)c[r];
            }
        }
    }
    __syncthreads();

    // GEMM2: T[g,o] = sum_mn W[g,mn] * Op[o,mn]  (M=32, N=32, K=1024)
    const int gt = wid >> 1, ot = wid & 1;
    const int grow = gt*16 + llo;
    f32x4 acc = (f32x4)(0.0f);
    #pragma unroll 8
    for (int ks = 0; ks < 32; ++ks) {
        int abyte = (grow*2048 + ks*64 + lhi*16) ^ ((grow & 7) << 4);
        h8 af = *(const h8*)(Wl + abyte);
        h8 bf = *(const h8*)(Ops + (ot*16 + llo)*1024 + ks*32 + 8*lhi);
        acc = __builtin_amdgcn_mfma_f32_16x16x32_f16(af, bf, acc, 0, 0, 0);
    }
    _Float16* Tow = To + (size_t)s*32768;
    h4 res;
    #pragma unroll
    for (int r = 0; r < 4; ++r) res[r] = (_Float16)acc[r];
    *(h4*)(Tow + (size_t)(ot*16 + llo)*1024 + f*32 + gt*16 + 4*lhi) = res;
}

// ---------------- main: out[b,s,o] = sum_fg (xL[b,f]*xR[b,g]) * T[s][o][fg] ----
// grid: 512 blocks (s = bid&31, btile = bid>>5, BT=128), 256 threads = 4 waves
__global__ __launch_bounds__(256) void main_kernel(
    const float* __restrict__ x, const _Float16* __restrict__ To,
    const float* __restrict__ bias, float* __restrict__ out)
{
    __shared__ __align__(16) char To_l[65536];   // [o][fg] f16, XOR-swizzled
    __shared__ _Float16 xlT[32][128];            // [f][b]
    __shared__ _Float16 xr[128][32];             // [b][g]

    const int bid = blockIdx.x;
    const int s = bid & 31;
    const int b0 = (bid >> 5) * 128;
    const int t = threadIdx.x, wid = t >> 6, l = t & 63;
    const int lo5 = l & 31, hi = l >> 5;

    // stage T[s] -> LDS, swizzled (reg-staged; swizzle forbids global_load_lds)
    const _Float16* Tos = To + (size_t)s*32768;
    #pragma unroll
    for (int i = 0; i < 16; ++i) {
        int idx = i*256 + t;                       // 16B unit
        uint4 v = *(const uint4*)((const char*)Tos + (size_t)idx*16);
        int o = idx >> 7;
        *(uint4*)(To_l + ((idx*16) ^ ((o & 7) << 4))) = v;
    }
    // stage x tile (fp32 -> f16): xlT transposed, xr row-major
    #pragma unroll
    for (int i = 0; i < 8; ++i) {
        int idx = i*256 + t, b = idx >> 4, c = idx & 15;
        float4 v = *(const float4*)(x + (size_t)(b0 + b)*2048 + s*64 + c*4);
        if (c < 8) {
            int f0 = c*4;
            xlT[f0+0][b] = (_Float16)v.x;
            xlT[f0+1][b] = (_Float16)v.y;
            xlT[f0+2][b] = (_Float16)v.z;
            xlT[f0+3][b] = (_Float16)v.w;
        } else {
            int g0 = (c - 8)*4;
            h4 w; w[0] = (_Float16)v.x; w[1] = (_Float16)v.y;
                  w[2] = (_Float16)v.z; w[3] = (_Float16)v.w;
            *(h4*)&xr[b][g0] = w;
        }
    }
    __syncthreads();

    // wave = one 32-row b-tile; 64 x mfma_32x32x16_f16 over K=1024
    const int b = wid*32 + lo5;                    // A row = lane&31
    h8 xrv0 = *(const h8*)&xr[b][8*hi];            // g = 8*hi..+7
    h8 xrv1 = *(const h8*)&xr[b][16 + 8*hi];       // g = 16+8*hi..+7
    const int sw = (lo5 & 7) << 4;
    const int base = lo5*2048 + hi*16;             // o = lo5 (B col = lane&31)
    f32x16 acc = (f32x16)(0.0f);
    #pragma unroll 8
    for (int f = 0; f < 32; ++f) {
        _Float16 xls = xlT[f][b];
        h8 z0 = xrv0 * xls;                        // 4x v_pk_mul_f16
        h8 bf0 = *(const h8*)(To_l + ((base + (2*f)*32) ^ sw));
        acc = __builtin_amdgcn_mfma_f32_32x32x16_f16(z0, bf0, acc, 0, 0, 0);
        h8 z1 = xrv1 * xls;
        h8 bf1 = *(const h8*)(To_l + ((base + (2*f+1)*32) ^ sw));
        acc = __builtin_amdgcn_mfma_f32_32x32x16_f16(z1, bf1, acc, 0, 0, 0);
    }
    const float bv = bias[s*32 + lo5];
    #pragma unroll
    for (int r = 0; r < 16; ++r) {
        int br = wid*32 + (r & 3) + 8*(r >> 2) + 4*hi;   // C row map (32x32)
        out[(size_t)(b0 + br)*1024 + s*32 + lo5] = acc[r] + bv;
    }
}

extern "C" void kernel_launch(void* const* d_in, const int* in_sizes, int n_in,
                              void* d_out, int out_size, void* d_ws, size_t ws_size,
                              hipStream_t stream) {
    const float* x    = (const float*)d_in[0];
    const float* L    = (const float*)d_in[1];
    const float* R    = (const float*)d_in[2];
    const float* O    = (const float*)d_in[3];
    const float* bias = (const float*)d_in[4];
    float* out = (float*)d_out;

    _Float16* Rb = (_Float16*)d_ws;          // 1M elems = 2 MB
    _Float16* Op = Rb + 1048576;             // 2 MB
    _Float16* To = Op + 1048576;             // 2 MB

    conv_kernel<<<dim3(1024, 2), 64, 0, stream>>>(R, O, Rb, Op);
    tmake_kernel<<<dim3(1024), 256, 0, stream>>>(L, Rb, Op, To);
    main_kernel<<<dim3(512), 256, 0, stream>>>(x, To, bias, out);
}

// Round 4
// 34.582 us; speedup vs baseline: 15.6087x; 1.2358x over previous
//
#include <hip/hip_runtime.h>
#include <hip/hip_bf16.h>

// B=2048, NF=64, FD=32, S=32, D=32, OD=32
typedef __attribute__((ext_vector_type(4)))  _Float16 h4;
typedef __attribute__((ext_vector_type(8)))  _Float16 h8;
typedef __attribute__((ext_vector_type(4)))  float f32x4;
typedef __attribute__((ext_vector_type(16))) float f32x16;

// ---------------- transpose/convert: Rb[s][g][n][a], Op[s][o][m*32+n] (f16) ----
__global__ __launch_bounds__(64) void conv_kernel(
    const float* __restrict__ Rg, const float* __restrict__ Og,
    _Float16* __restrict__ Rb, _Float16* __restrict__ Op)
{
    __shared__ float tile[32][33];
    const int which = blockIdx.y;
    const int s = blockIdx.x >> 5, q = blockIdx.x & 31;   // q = g (Rb) or m (Op)
    const int t = threadIdx.x, tl = t & 31, th = t >> 5;

    if (which == 0) {
        // Rb[s][g][n][a] = R[s][g][a][n]
        #pragma unroll
        for (int j = 0; j < 16; ++j) {
            int ar = 2*j + th;
            tile[tl][ar] = Rg[(((size_t)s*32 + q)*32 + ar)*32 + tl];   // tile[n][a]
        }
        __syncthreads();
        #pragma unroll
        for (int j = 0; j < 16; ++j) {
            int nr = 2*j + th;
            Rb[(((size_t)s*32 + q)*32 + nr)*32 + tl] = (_Float16)tile[nr][tl];
        }
    } else {
        // Op[s][o][m*32+n] = O[s][m][n][o]
        #pragma unroll
        for (int j = 0; j < 16; ++j) {
            int nr = 2*j + th;
            tile[tl][nr] = Og[(((size_t)s*32 + q)*32 + nr)*32 + tl];   // tile[o][n]
        }
        __syncthreads();
        #pragma unroll
        for (int j = 0; j < 16; ++j) {
            int orow = 2*j + th;
            Op[((size_t)s*32 + orow)*1024 + q*32 + tl] = (_Float16)tile[orow][tl];
        }
    }
}

// ---------------- T build: Tp[s][ks=f*2+(g>>4)][o][kk=g&15] ----
// T[fg,o] = sum_mn (sum_a L[s,f,a,m] R[s,g,a,n]) * O[s,m,n,o]
// grid: 1024 blocks (s = bid&31 -> XCD-local, f = bid>>5), 256 threads = 4 waves
__global__ __launch_bounds__(256) void tmake_kernel(
    const float* __restrict__ Lg, const _Float16* __restrict__ Rb,
    const _Float16* __restrict__ Op, _Float16* __restrict__ Tp)
{
    __shared__ __align__(16) char Wl[65536];   // W[g][m*32+n] f16, XOR-swizzled
    __shared__ float Ltile[32][33];            // L[s,f][a][m]
    __shared__ __align__(16) char Opc[8192];   // Op k-chunk [o][128k] f16, swizzled

    const int bid = blockIdx.x;
    const int s = bid & 31, f = bid >> 5;
    const int t = threadIdx.x, wid = t >> 6, l = t & 63;
    const int llo = l & 15, lhi = l >> 4;

    #pragma unroll
    for (int i = 0; i < 4; ++i) {
        int idx = i*256 + t, a = idx >> 5, m = idx & 31;
        Ltile[a][m] = Lg[(((size_t)s*32 + f)*32 + a)*32 + m];
    }
    __syncthreads();

    h8 afrag[2];
    #pragma unroll
    for (int mt = 0; mt < 2; ++mt)
        #pragma unroll
        for (int j = 0; j < 8; ++j)
            afrag[mt][j] = (_Float16)Ltile[8*lhi + j][mt*16 + llo];

    const _Float16* Rbs = Rb + (size_t)s*32768;
    const _Float16* Ops = Op + (size_t)s*32768;

    // GEMM1: W[m, gn] = sum_a Ltile[m,a] * Rb[gn,a]  (M=32, N=1024, K=32)
    #pragma unroll 4
    for (int nt = 0; nt < 16; ++nt) {
        int col = (wid*16 + nt)*16 + llo;                 // gn (coalesced 1KB/instr)
        h8 bfrag = *(const h8*)(Rbs + col*32 + 8*lhi);
        int g = col >> 5, n = col & 31;
        #pragma unroll
        for (int mt = 0; mt < 2; ++mt) {
            f32x4 c = __builtin_amdgcn_mfma_f32_16x16x32_f16(afrag[mt], bfrag, (f32x4)(0.0f), 0, 0, 0);
            #pragma unroll
            for (int r = 0; r < 4; ++r) {
                int m = mt*16 + 4*lhi + r;
                int byte = (g*2048 + (m*32 + n)*2) ^ ((g & 7) << 4);
                *(_Float16*)(Wl + byte) = (_Float16)c[r];
            }
        }
    }
    __syncthreads();

    // GEMM2: T[g,o] = sum_mn W[g,mn] * Op[o,mn]  (K=1024, 8 chunks of 128)
    const int gt = wid >> 1, ot = wid & 1;
    const int grow = gt*16 + llo;
    const int orow = ot*16 + llo;
    f32x4 acc = (f32x4)(0.0f);
    for (int c = 0; c < 8; ++c) {
        {   // stage 8KB chunk, coalesced (8 threads x 2x16B per o-row)
            int o = t >> 3, j = t & 7;
            uint4 v0 = *(const uint4*)(Ops + o*1024 + c*128 + j*8);
            uint4 v1 = *(const uint4*)(Ops + o*1024 + c*128 + (j+8)*8);
            *(uint4*)(Opc + ((o*256 + j*16)     ^ ((o & 7) << 4))) = v0;
            *(uint4*)(Opc + ((o*256 + (j+8)*16) ^ ((o & 7) << 4))) = v1;
        }
        __syncthreads();
        #pragma unroll
        for (int ksl = 0; ksl < 4; ++ksl) {
            int ks = c*4 + ksl;
            int abyte = (grow*2048 + ks*64 + lhi*16) ^ ((grow & 7) << 4);
            h8 af = *(const h8*)(Wl + abyte);
            h8 bf = *(const h8*)(Opc + ((orow*256 + ksl*64 + lhi*16) ^ ((orow & 7) << 4)));
            acc = __builtin_amdgcn_mfma_f32_16x16x32_f16(af, bf, acc, 0, 0, 0);
        }
        __syncthreads();
    }
    // D 16x16: col(lane&15)=o-within-tile, row=4*lhi+r = g-within-tile
    _Float16* Tps = Tp + (size_t)s*32768;
    h4 res;
    #pragma unroll
    for (int r = 0; r < 4; ++r) res[r] = (_Float16)acc[r];
    *(h4*)(Tps + ((f*2 + gt)*32 + orow)*16 + 4*lhi) = res;
}

// ---------------- main: out[b,s,o] = sum_k (xL[b,f]*xR[b,g]) * Tp[s][k][o] ----
// grid: 256 blocks (s = bid&31, btile = bid>>5, BT=256), 256 threads = 4 waves
// wave owns 2 b-subtiles (r=2 bf sharing); Tp staged in 4 chunks (T14 pipeline)
__global__ __launch_bounds__(256) void main_kernel(
    const float* __restrict__ x, const _Float16* __restrict__ Tp,
    const float* __restrict__ bias, float* __restrict__ out)
{
    __shared__ __align__(16) char To2[65536];   // [ks][o][kk] linear, conflict-free
    __shared__ __align__(16) char xl2[16384];   // [blk][b][8] f16
    __shared__ __align__(16) char xr2[16384];   // [blk=gh*2+hi][b][8] f16

    const int bid = blockIdx.x;
    const int s = bid & 31;
    const int b0 = (bid >> 5) * 256;
    const int t = threadIdx.x;
    const int l = t & 63, wid = t >> 6;
    const int lo5 = l & 31, hi = l >> 5;

    const char* Tps = (const char*)(Tp + (size_t)s*32768);

    // issue To chunk 0 early
    uint4 tv[4];
    #pragma unroll
    for (int r = 0; r < 4; ++r)
        tv[r] = *(const uint4*)(Tps + r*4096 + t*16);

    // stage x (coalesced float4), convert to f16, split xl/xr
    #pragma unroll
    for (int i = 0; i < 16; ++i) {
        int idx = i*256 + t, b = idx >> 4, c = idx & 15;
        float4 v = *(const float4*)(x + (size_t)(b0 + b)*2048 + s*64 + c*4);
        h4 w; w[0] = (_Float16)v.x; w[1] = (_Float16)v.y;
              w[2] = (_Float16)v.z; w[3] = (_Float16)v.w;
        if (c < 8) *(h4*)(xl2 + (c >> 1)*4096 + b*16 + (c & 1)*8) = w;
        else { int c2 = c - 8; *(h4*)(xr2 + (c2 >> 1)*4096 + b*16 + (c2 & 1)*8) = w; }
    }
    #pragma unroll
    for (int r = 0; r < 4; ++r)
        *(uint4*)(To2 + r*4096 + t*16) = tv[r];
    __syncthreads();

    // hoist xl rows (full 32 f16) and xr frags (2 gh-halves) into registers
    const int sub0 = wid*2;
    h8 xlr_[2][4];
    h8 xrr_[2][2];
    #pragma unroll
    for (int sb = 0; sb < 2; ++sb) {
        int b = (sub0 + sb)*32 + lo5;
        #pragma unroll
        for (int blk = 0; blk < 4; ++blk)
            xlr_[sb][blk] = *(const h8*)(xl2 + blk*4096 + b*16);
        #pragma unroll
        for (int gh = 0; gh < 2; ++gh)
            xrr_[sb][gh] = *(const h8*)(xr2 + (gh*2 + hi)*4096 + b*16);
    }

    f32x16 acc0 = (f32x16)(0.0f), acc1 = (f32x16)(0.0f);

    #pragma unroll
    for (int c = 0; c < 4; ++c) {
        if (c < 3) {   // issue next chunk's loads early (hide L2 latency under MFMA)
            #pragma unroll
            for (int r = 0; r < 4; ++r)
                tv[r] = *(const uint4*)(Tps + (c + 1)*16384 + r*4096 + t*16);
        }
        #pragma unroll
        for (int ksl = 0; ksl < 16; ++ksl) {
            int ks = c*16 + ksl;
            int f = ks >> 1, gh = ks & 1;
            h8 bf = *(const h8*)(To2 + ks*1024 + lo5*32 + hi*16);  // contiguous 1KB/wave
            _Float16 xs0 = xlr_[0][f >> 3][f & 7];
            h8 z0 = xrr_[0][gh] * xs0;
            acc0 = __builtin_amdgcn_mfma_f32_32x32x16_f16(z0, bf, acc0, 0, 0, 0);
            _Float16 xs1 = xlr_[1][f >> 3][f & 7];
            h8 z1 = xrr_[1][gh] * xs1;
            acc1 = __builtin_amdgcn_mfma_f32_32x32x16_f16(z1, bf, acc1, 0, 0, 0);
        }
        if (c < 3) {   // write-late into disjoint region, then barrier
            #pragma unroll
            for (int r = 0; r < 4; ++r)
                *(uint4*)(To2 + (c + 1)*16384 + r*4096 + t*16) = tv[r];
            __syncthreads();
        }
    }

    const float bv = bias[s*32 + lo5];
    #pragma unroll
    for (int r = 0; r < 16; ++r) {
        int rowoff = (r & 3) + 8*(r >> 2) + 4*hi;   // 32x32 C/D row map
        out[(size_t)(b0 + sub0*32 + rowoff)*1024 + s*32 + lo5] = acc0[r] + bv;
        out[(size_t)(b0 + sub0*32 + 32 + rowoff)*1024 + s*32 + lo5] = acc1[r] + bv;
    }
}

extern "C" void kernel_launch(void* const* d_in, const int* in_sizes, int n_in,
                              void* d_out, int out_size, void* d_ws, size_t ws_size,
                              hipStream_t stream) {
    const float* x    = (const float*)d_in[0];
    const float* L    = (const float*)d_in[1];
    const float* R    = (const float*)d_in[2];
    const float* O    = (const float*)d_in[3];
    const float* bias = (const float*)d_in[4];
    float* out = (float*)d_out;

    _Float16* Rb = (_Float16*)d_ws;          // 2 MB
    _Float16* Op = Rb + 1048576;             // 2 MB
    _Float16* Tp = Op + 1048576;             // 2 MB

    conv_kernel<<<dim3(1024, 2), 64, 0, stream>>>(R, O, Rb, Op);
    tmake_kernel<<<dim3(1024), 256, 0, stream>>>(L, Rb, Op, Tp);
    main_kernel<<<dim3(256), 256, 0, stream>>>(x, Tp, bias, out);
}

// Round 5
// 33.986 us; speedup vs baseline: 15.8825x; 1.0175x over previous
//
#include <hip/hip_runtime.h>
#include <hip/hip_bf16.h>

// B=2048, NF=64, FD=32, S=32, D=32, OD=32
typedef __attribute__((ext_vector_type(4)))  _Float16 h4;
typedef __attribute__((ext_vector_type(8)))  _Float16 h8;
typedef __attribute__((ext_vector_type(4)))  float f32x4;
typedef __attribute__((ext_vector_type(16))) float f32x16;

// ---------------- conv: Rb[s][g][n][a] f16 ; Opp[s][c8][o][kk] bytes,
// c8 = (m*32+n)>>3, kk = n&7  (16B per (c8,o) unit) ----
__global__ __launch_bounds__(64) void conv_kernel(
    const float* __restrict__ Rg, const float* __restrict__ Og,
    _Float16* __restrict__ Rb, char* __restrict__ Opp)
{
    __shared__ float tile[32][33];
    const int bid = blockIdx.x;
    const int s = bid & 31, q = (bid >> 5) & 31, which = bid >> 10;
    const int t = threadIdx.x, tl = t & 31, th = t >> 5;

    if (which == 0) {
        // tile[n][a] = R[s, g=q][a][n]
        #pragma unroll
        for (int j = 0; j < 16; ++j) {
            int ar = 2*j + th;
            tile[tl][ar] = Rg[(((size_t)s*32 + q)*32 + ar)*32 + tl];
        }
        __syncthreads();
        _Float16* dst = Rb + ((size_t)s*32 + q)*1024;   // [n][a]
        #pragma unroll
        for (int it = 0; it < 4; ++it) {
            int nr = it*8 + (t >> 3), a0 = (t & 7)*4;
            h4 w;
            #pragma unroll
            for (int k = 0; k < 4; ++k) w[k] = (_Float16)tile[nr][a0 + k];
            *(h4*)(dst + nr*32 + a0) = w;
        }
    } else {
        // tile[o][n] = O[s][m=q][n][o]
        #pragma unroll
        for (int j = 0; j < 16; ++j) {
            int nr = 2*j + th;
            tile[tl][nr] = Og[(((size_t)s*32 + q)*32 + nr)*32 + tl];
        }
        __syncthreads();
        char* dst = Opp + (size_t)s*65536 + q*2048;     // c8 = q*4 + (n>>3)
        int o = t & 31, cq = t >> 5;
        #pragma unroll
        for (int it = 0; it < 2; ++it) {
            int c = it*2 + cq;                          // n-chunk 0..3
            h8 w;
            #pragma unroll
            for (int k = 0; k < 8; ++k) w[k] = (_Float16)tile[o][c*8 + k];
            *(h8*)(dst + c*512 + o*16) = w;
        }
    }
}

// ---------------- tmake: Tp[s][ks=f*2+gt][o][kk] (f16, byte = ks*1024 + o*32 + kk*2)
// W[g][mn] swizzle: byte = (g*2048 + m*64 + n*2) ^ (((g&7)^(m&7))<<4)
// grid 1024 = (s = bid&31, f = bid>>5), 256 thr = 4 waves ----
__global__ __launch_bounds__(256, 2) void tmake_kernel(
    const float* __restrict__ Lg, const _Float16* __restrict__ Rb,
    const char* __restrict__ Opp, char* __restrict__ Tp)
{
    __shared__ __align__(16) char Wl[65536];
    const int bid = blockIdx.x;
    const int s = bid & 31, f = bid >> 5;
    const int t = threadIdx.x, wid = t >> 6, l = t & 63;
    const int llo = l & 15, lhi = l >> 4;

    // L-frag (B-side of GEMM1): bfr[mt][j] = L[s,f][a=8*lhi+j][m=mt*16+llo]
    const float* Lsf = Lg + ((size_t)s*32 + f)*1024;
    h8 bfr[2];
    #pragma unroll
    for (int mt = 0; mt < 2; ++mt)
        #pragma unroll
        for (int j = 0; j < 8; ++j)
            bfr[mt][j] = (_Float16)Lsf[(8*lhi + j)*32 + mt*16 + llo];

    const _Float16* Rbs = Rb + (size_t)s*32768;

    // GEMM1: W[gn, m] = sum_a Rb[gn, a] * L[a, m]; D cols = m, rows = gn
    #pragma unroll 4
    for (int nt = 0; nt < 16; ++nt) {
        int gnb = (wid*16 + nt)*16;
        h8 af = *(const h8*)(Rbs + (gnb + llo)*32 + 8*lhi);   // coalesced 1KB
        int g = gnb >> 5;
        int nbase = (gnb & 31) + 4*lhi;
        #pragma unroll
        for (int mt = 0; mt < 2; ++mt) {
            f32x4 d = __builtin_amdgcn_mfma_f32_16x16x32_f16(af, bfr[mt], (f32x4)(0.f), 0, 0, 0);
            int m = mt*16 + llo;
            h4 w;
            #pragma unroll
            for (int r = 0; r < 4; ++r) w[r] = (_Float16)d[r];
            int byte = (g*2048 + m*64 + nbase*2) ^ ((((g & 7) ^ (m & 7))) << 4);
            *(h4*)(Wl + byte) = w;
        }
    }
    __syncthreads();

    // GEMM2: T[g,o] = sum_mn W[g,mn] * Opp[o,mn]; waves: ot = wid&1, kq = wid>>1
    const int ot = wid & 1, kq = wid >> 1;
    const int orow = ot*16 + llo;
    const char* Opps = Opp + (size_t)s*65536;
    f32x4 acc0 = (f32x4)(0.f), acc1 = (f32x4)(0.f);
    #pragma unroll 4
    for (int ksl = 0; ksl < 16; ++ksl) {
        int ks = kq*16 + ksl;                               // m = ks
        h8 bf = *(const h8*)(Opps + (ks*4 + lhi)*512 + orow*16);
        {   // gt = 0
            int grow = llo;
            int byte = (grow*2048 + ks*64 + lhi*16) ^ ((((grow & 7) ^ (ks & 7))) << 4);
            h8 af = *(const h8*)(Wl + byte);
            acc0 = __builtin_amdgcn_mfma_f32_16x16x32_f16(af, bf, acc0, 0, 0, 0);
        }
        {   // gt = 1
            int grow = 16 + llo;
            int byte = (grow*2048 + ks*64 + lhi*16) ^ ((((grow & 7) ^ (ks & 7))) << 4);
            h8 af = *(const h8*)(Wl + byte);
            acc1 = __builtin_amdgcn_mfma_f32_16x16x32_f16(af, bf, acc1, 0, 0, 0);
        }
    }
    // k-quarter reduce (reuse Wl head after all reads complete)
    __syncthreads();
    if (kq == 1) {
        *(f32x4*)(Wl + ((ot*2 + 0)*64 + l)*16) = acc0;
        *(f32x4*)(Wl + ((ot*2 + 1)*64 + l)*16) = acc1;
    }
    __syncthreads();
    if (kq == 0) {
        acc0 += *(const f32x4*)(Wl + ((ot*2 + 0)*64 + l)*16);
        acc1 += *(const f32x4*)(Wl + ((ot*2 + 1)*64 + l)*16);
        char* Tps = Tp + (size_t)s*65536;
        h4 w0, w1;
        #pragma unroll
        for (int r = 0; r < 4; ++r) { w0[r] = (_Float16)acc0[r]; w1[r] = (_Float16)acc1[r]; }
        *(h4*)(Tps + (f*2 + 0)*1024 + orow*32 + lhi*8) = w0;   // D row = g = gt*16+4*lhi+r
        *(h4*)(Tps + (f*2 + 1)*1024 + orow*32 + lhi*8) = w1;
    }
}

// ---------------- main: out[b,s,o] = sum_k (xL[b,f]*xR[b,g]) * Tp[s][k][o]
// grid 512 = (s = bid&31, btile = bid>>5, BT=128), 256 thr = 4 waves
// wave = (kh = wid&1 k-half, sbp = wid>>1 b-subtile-pair); 2 sub/wave share bf ----
__global__ __launch_bounds__(256, 3) void main_kernel(
    const float* __restrict__ x, const char* __restrict__ Tp,
    const float* __restrict__ bias, float* __restrict__ out)
{
    __shared__ __align__(16) char Tb0[16384];
    __shared__ __align__(16) char Tb1[16384];
    __shared__ __align__(16) char xl2[8192];   // [f>>3][b][8] f16
    __shared__ __align__(16) char xr2[8192];   // [g>>3][b][8] f16

    const int bid = blockIdx.x;
    const int s = bid & 31;
    const int b0 = (bid >> 5) * 128;
    const int t = threadIdx.x, wid = t >> 6, l = t & 63;
    const int lo5 = l & 31, hi = l >> 5;
    const int kh = wid & 1, sbp = wid >> 1;

    const char* Tps = Tp + (size_t)s*65536;

    // issue chunk-0 loads early
    uint4 tv[4];
    #pragma unroll
    for (int i = 0; i < 4; ++i)
        tv[i] = *(const uint4*)(Tps + (i*256 + t)*16);

    // stage x (32KB fp32, coalesced float4) -> f16 xl2/xr2
    #pragma unroll
    for (int i = 0; i < 8; ++i) {
        int idx = i*256 + t, b = idx >> 4, c = idx & 15;
        float4 v = *(const float4*)(x + (size_t)(b0 + b)*2048 + s*64 + c*4);
        h4 w; w[0] = (_Float16)v.x; w[1] = (_Float16)v.y;
              w[2] = (_Float16)v.z; w[3] = (_Float16)v.w;
        if (c < 8) *(h4*)(xl2 + (c >> 1)*2048 + b*16 + (c & 1)*8) = w;
        else { int c2 = c - 8; *(h4*)(xr2 + (c2 >> 1)*2048 + b*16 + (c2 & 1)*8) = w; }
    }
    #pragma unroll
    for (int i = 0; i < 4; ++i)
        *(uint4*)(Tb0 + (i*256 + t)*16) = tv[i];
    #pragma unroll
    for (int i = 0; i < 4; ++i)                 // issue chunk-1
        tv[i] = *(const uint4*)(Tps + 16384 + (i*256 + t)*16);
    __syncthreads();

    // register hoists (all indices compile-time)
    h4 xlh[2][4];   // [sb][chunk]: f = c*8 + kh*4 + (i>>1)
    h8 xrh[2][2];   // [sb][gh]
    #pragma unroll
    for (int sb = 0; sb < 2; ++sb) {
        int b = sbp*64 + sb*32 + lo5;
        #pragma unroll
        for (int c = 0; c < 4; ++c)
            xlh[sb][c] = *(const h4*)(xl2 + c*2048 + b*16 + kh*8);
        #pragma unroll
        for (int gh = 0; gh < 2; ++gh)
            xrh[sb][gh] = *(const h8*)(xr2 + (gh*2 + hi)*2048 + b*16);
    }

    f32x16 acc0 = (f32x16)(0.f), acc1 = (f32x16)(0.f);

    #pragma unroll
    for (int c = 0; c < 4; ++c) {
        const char* Tc = (c & 1) ? Tb1 : Tb0;
        #pragma unroll
        for (int i = 0; i < 8; ++i) {
            int ksl = kh*8 + i;                               // ks = c*16 + ksl
            h8 bf = *(const h8*)(Tc + ksl*1024 + lo5*32 + hi*16);
            _Float16 x0 = xlh[0][c][i >> 1];
            _Float16 x1 = xlh[1][c][i >> 1];
            h8 z0 = xrh[0][i & 1] * x0;
            acc0 = __builtin_amdgcn_mfma_f32_32x32x16_f16(z0, bf, acc0, 0, 0, 0);
            h8 z1 = xrh[1][i & 1] * x1;
            acc1 = __builtin_amdgcn_mfma_f32_32x32x16_f16(z1, bf, acc1, 0, 0, 0);
        }
        if (c < 3) {
            char* Tn = (c & 1) ? Tb0 : Tb1;                   // buffer for chunk c+1
            #pragma unroll
            for (int i = 0; i < 4; ++i)
                *(uint4*)(Tn + (i*256 + t)*16) = tv[i];
            if (c < 2) {
                #pragma unroll
                for (int i = 0; i < 4; ++i)                   // issue chunk c+2
                    tv[i] = *(const uint4*)(Tps + (c + 2)*16384 + (i*256 + t)*16);
            }
            __syncthreads();
        }
    }

    // k-half reduce: kh=1 publish to LDS (xl2/xr2 free), kh=0 finalize
    __syncthreads();
    if (kh == 1) {
        #pragma unroll
        for (int rq = 0; rq < 4; ++rq) {
            f32x4 p0, p1;
            #pragma unroll
            for (int rr = 0; rr < 4; ++rr) { p0[rr] = acc0[rq*4 + rr]; p1[rr] = acc1[rq*4 + rr]; }
            *(f32x4*)(xl2 + sbp*4096 + rq*1024 + l*16) = p0;
            *(f32x4*)(xr2 + sbp*4096 + rq*1024 + l*16) = p1;
        }
    }
    __syncthreads();
    if (kh == 0) {
        const float bv = bias[s*32 + lo5];
        #pragma unroll
        for (int rq = 0; rq < 4; ++rq) {
            f32x4 p0 = *(const f32x4*)(xl2 + sbp*4096 + rq*1024 + l*16);
            f32x4 p1 = *(const f32x4*)(xr2 + sbp*4096 + rq*1024 + l*16);
            #pragma unroll
            for (int rr = 0; rr < 4; ++rr) {
                int r = rq*4 + rr;
                int rowoff = (r & 3) + 8*(r >> 2) + 4*hi;     // 32x32 C/D row map
                out[(size_t)(b0 + sbp*64 + rowoff)*1024 + s*32 + lo5] = acc0[r] + p0[rr] + bv;
                out[(size_t)(b0 + sbp*64 + 32 + rowoff)*1024 + s*32 + lo5] = acc1[r] + p1[rr] + bv;
            }
        }
    }
}

extern "C" void kernel_launch(void* const* d_in, const int* in_sizes, int n_in,
                              void* d_out, int out_size, void* d_ws, size_t ws_size,
                              hipStream_t stream) {
    const float* x    = (const float*)d_in[0];
    const float* L    = (const float*)d_in[1];
    const float* R    = (const float*)d_in[2];
    const float* O    = (const float*)d_in[3];
    const float* bias = (const float*)d_in[4];
    float* out = (float*)d_out;

    _Float16* Rb  = (_Float16*)d_ws;                 // 2 MB
    char*     Opp = (char*)(Rb + 1048576);           // 2 MB
    char*     Tp  = Opp + 2097152;                   // 2 MB

    conv_kernel<<<dim3(2048), 64, 0, stream>>>(R, O, Rb, Opp);
    tmake_kernel<<<dim3(1024), 256, 0, stream>>>(L, Rb, Opp, Tp);
    main_kernel<<<dim3(512), 256, 0, stream>>>(x, Tp, bias, out);
}